// Round 4
// baseline (1155.686 us; speedup 1.0000x reference)
//
#include <hip/hip_runtime.h>
#include <math.h>

#define HID 32
#define BS 256

// ---------------- structure-building kernels ----------------

__global__ void k_zero_i(int* __restrict__ p, int n) {
  int i = blockIdx.x * BS + threadIdx.x;
  if (i < n) p[i] = 0;
}

// cnt[dst]++ over M edges
__global__ void k_count(const int* __restrict__ ei, int* __restrict__ cnt, int M) {
  int e = blockIdx.x * BS + threadIdx.x;
  if (e < M) atomicAdd(&cnt[ei[M + e]], 1);
}

// per-block sums of cnt -> bsum[NB]
__global__ void k_bsum(const int* __restrict__ cnt, int* __restrict__ bsum, int T) {
  __shared__ int s[BS];
  int i = blockIdx.x * BS + threadIdx.x;
  s[threadIdx.x] = (i < T) ? cnt[i] : 0;
  __syncthreads();
  for (int off = BS / 2; off > 0; off >>= 1) {
    if (threadIdx.x < off) s[threadIdx.x] += s[threadIdx.x + off];
    __syncthreads();
  }
  if (threadIdx.x == 0) bsum[blockIdx.x] = s[0];
}

// single-block exclusive scan of bsum[0..NB) -> boff[0..NB)
__global__ void k_scanb(const int* __restrict__ bsum, int* __restrict__ boff, int NB) {
  __shared__ int buf[BS];
  __shared__ int run;
  if (threadIdx.x == 0) run = 0;
  __syncthreads();
  for (int base = 0; base < NB; base += BS) {
    int i = base + threadIdx.x;
    int v = (i < NB) ? bsum[i] : 0;
    buf[threadIdx.x] = v;
    __syncthreads();
    for (int off = 1; off < BS; off <<= 1) {
      int t = buf[threadIdx.x];
      int u = (threadIdx.x >= off) ? buf[threadIdx.x - off] : 0;
      __syncthreads();
      buf[threadIdx.x] = t + u;
      __syncthreads();
    }
    int incl = buf[threadIdx.x];
    if (i < NB) boff[i] = run + incl - v;  // exclusive
    __syncthreads();
    if (threadIdx.x == BS - 1) run += buf[BS - 1];
    __syncthreads();
  }
}

// row_ptr[i] = boff[blk] + in-block exclusive scan of cnt; row_ptr[T] = M
__global__ void k_scan3(const int* __restrict__ cnt, const int* __restrict__ boff,
                        int* __restrict__ row_ptr, int T, int M) {
  __shared__ int buf[BS];
  int i = blockIdx.x * BS + threadIdx.x;
  int v = (i < T) ? cnt[i] : 0;
  buf[threadIdx.x] = v;
  __syncthreads();
  for (int off = 1; off < BS; off <<= 1) {
    int t = buf[threadIdx.x];
    int u = (threadIdx.x >= off) ? buf[threadIdx.x - off] : 0;
    __syncthreads();
    buf[threadIdx.x] = t + u;
    __syncthreads();
  }
  int incl = buf[threadIdx.x];
  if (i < T) row_ptr[i] = boff[blockIdx.x] + incl - v;
  if (i == 0) row_ptr[T] = M;
}

__global__ void k_copy_i(const int* __restrict__ a, int* __restrict__ b, int n) {
  int i = blockIdx.x * BS + threadIdx.x;
  if (i < n) b[i] = a[i];
}

// scatter src indices into CSR order by dst
__global__ void k_fill(const int* __restrict__ ei, int* __restrict__ cursor,
                       int* __restrict__ srt, int M) {
  int e = blockIdx.x * BS + threadIdx.x;
  if (e >= M) return;
  int s = ei[e], d = ei[M + e];
  int pos = atomicAdd(&cursor[d], 1);
  srt[pos] = s;
}

// ---------------- math kernels ----------------

// msg[e] = ec[e]/cnt[e]
__global__ void k_msg(const float* __restrict__ ec, const float* __restrict__ cnt,
                      float* __restrict__ msg, int E) {
  int i = blockIdx.x * BS + threadIdx.x;
  if (i < E) msg[i] = ec[i] / cnt[i];
}

// step 1: tri4[i] = (t12 + msg[c12], t13 + msg[c13], t23 + msg[c23], dis_i)
__global__ void k_step1pack(const float* __restrict__ msg,
                            const float* __restrict__ t12, const float* __restrict__ t13,
                            const float* __restrict__ t23,
                            const int* __restrict__ c12, const int* __restrict__ c13,
                            const int* __restrict__ c23,
                            const int* __restrict__ row_ptr,
                            float4* __restrict__ tri4, int T) {
  int i = blockIdx.x * BS + threadIdx.x;
  if (i >= T) return;
  int a = c12[i], b = c13[i], c = c23[i];
  float4 v;
  v.x = t12[i] + msg[a];
  v.y = t13[i] + msg[b];
  v.z = t23[i] + msg[c];
  v.w = rsqrtf((float)(row_ptr[i + 1] - row_ptr[i]) + 1.0f);
  tri4[i] = v;
}

// out_ec init: where(cnt>0, 0, ec)
__global__ void k_initec(const float* __restrict__ ec, const float* __restrict__ cnt,
                         float* __restrict__ oec, int E) {
  int i = blockIdx.x * BS + threadIdx.x;
  if (i < E) oec[i] = (cnt[i] > 0.0f) ? 0.0f : ec[i];
}

// edge-parallel gather: EV[e] = src[srt[e]]   (2 independent gathers per thread)
// Each lane's gather is independent -> a wave64 load puts 64 cacheline
// requests in flight -> throughput-regime, not latency-regime.
__global__ __launch_bounds__(BS) void k_gather(const int* __restrict__ srt,
                                               const float4* __restrict__ src,
                                               float4* __restrict__ EV, int M) {
  int t = blockIdx.x * BS + threadIdx.x;
  int half = (M + 1) >> 1;
  if (t >= half) return;
  int t2 = t + half;
  int s0 = srt[t];
  int s1 = (t2 < M) ? srt[t2] : s0;
  float4 v0 = src[s0];
  float4 v1 = src[s1];
  EV[t] = v0;
  if (t2 < M) EV[t2] = v1;
}

// layer-1 aggregate, sequential consume of EV:
// G4[i].xyz = sum_{e in row} EV[e].xyz * EV[e].w * dis_i + tri4[i].xyz*dis_i^2 ; G4[i].w = dis_i
__global__ __launch_bounds__(BS) void k_agg1c(const int* __restrict__ row_ptr,
                                              const float4* __restrict__ EV,
                                              const float4* __restrict__ tri4,
                                              float4* __restrict__ G4, int T) {
  int i = blockIdx.x * BS + threadIdx.x;
  if (i >= T) return;
  int r0 = row_ptr[i], r1 = row_ptr[i + 1];
  float4 ts = tri4[i];
  float di = ts.w;
  float d2 = di * di;
  float ax = ts.x * d2, ay = ts.y * d2, az = ts.z * d2;
  for (int e = r0; e < r1; ++e) {
    float4 v = EV[e];
    float w = v.w * di;
    ax = fmaf(v.x, w, ax);
    ay = fmaf(v.y, w, ay);
    az = fmaf(v.z, w, az);
  }
  float4 o;
  o.x = ax; o.y = ay; o.z = az; o.w = di;
  G4[i] = o;
}

// fused: layer-1 transform (W1,b1,relu on the fly) -> layer-2 aggregate in registers
//        -> x2 = relu(agg@W2+b2) -> delta = x2@Wout+bout -> t updates + edge scatter
// All memory access sequential except the 3 output-edge atomics.
__global__ __launch_bounds__(BS) void k_l2head(
    const int* __restrict__ row_ptr, const float4* __restrict__ EV,
    const float4* __restrict__ G4, const float4* __restrict__ tri4,
    const float* __restrict__ W1, const float* __restrict__ b1,
    const float* __restrict__ W2, const float* __restrict__ b2,
    const float* __restrict__ Wout, const float* __restrict__ bout,
    const int* __restrict__ c12, const int* __restrict__ c13,
    const int* __restrict__ c23,
    float* __restrict__ o12, float* __restrict__ o13, float* __restrict__ o23,
    float* __restrict__ oec, int T) {
  __shared__ float w1s[3 * HID];
  __shared__ float b1s[HID];
  __shared__ float w2s[HID * HID];
  __shared__ float b2s[HID];
  __shared__ float wos[HID * 3];
  __shared__ float bos[3];
  for (int j = threadIdx.x; j < 3 * HID; j += BS) w1s[j] = W1[j];
  for (int j = threadIdx.x; j < HID; j += BS) b1s[j] = b1[j];
  for (int j = threadIdx.x; j < HID * HID; j += BS) w2s[j] = W2[j];
  for (int j = threadIdx.x; j < HID; j += BS) b2s[j] = b2[j];
  for (int j = threadIdx.x; j < HID * 3; j += BS) wos[j] = Wout[j];
  if (threadIdx.x < 3) bos[threadIdx.x] = bout[threadIdx.x];
  __syncthreads();

  int i = blockIdx.x * BS + threadIdx.x;
  if (i >= T) return;
  int r0 = row_ptr[i], r1 = row_ptr[i + 1];
  float4 gi = G4[i];
  float di = gi.w;
  float d2 = di * di;

  // layer-2 aggregate in registers; h1 recomputed on the fly
  float acc[HID];
#pragma unroll
  for (int h = 0; h < HID; ++h) {
    float v = fmaf(gi.x, w1s[h], fmaf(gi.y, w1s[HID + h], fmaf(gi.z, w1s[2 * HID + h], b1s[h])));
    acc[h] = fmaxf(v, 0.0f) * d2;  // self-loop term
  }
  for (int e = r0; e < r1; ++e) {
    float4 g = EV[e];
    float w = g.w * di;
#pragma unroll
    for (int h = 0; h < HID; ++h) {
      float v = fmaf(g.x, w1s[h], fmaf(g.y, w1s[HID + h], fmaf(g.z, w1s[2 * HID + h], b1s[h])));
      acc[h] = fmaf(fmaxf(v, 0.0f), w, acc[h]);
    }
  }

  // x2 = relu(acc @ W2 + b2); delta = x2 @ Wout + bout  (x2 never stored)
  float d0 = bos[0], d1 = bos[1], dd2 = bos[2];
  for (int hp = 0; hp < HID; ++hp) {
    float v = b2s[hp];
#pragma unroll
    for (int h = 0; h < HID; ++h) v = fmaf(acc[h], w2s[h * HID + hp], v);
    v = fmaxf(v, 0.0f);
    d0 = fmaf(v, wos[hp * 3 + 0], d0);
    d1 = fmaf(v, wos[hp * 3 + 1], d1);
    dd2 = fmaf(v, wos[hp * 3 + 2], dd2);
  }

  float4 tp = tri4[i];
  o12[i] = tp.x - d0;
  o13[i] = tp.y - d1;
  o23[i] = tp.z - dd2;
  unsafeAtomicAdd(&oec[c12[i]], d0);
  unsafeAtomicAdd(&oec[c13[i]], d1);
  unsafeAtomicAdd(&oec[c23[i]], dd2);
}

// ---------------- launch ----------------

extern "C" void kernel_launch(void* const* d_in, const int* in_sizes, int n_in,
                              void* d_out, int out_size, void* d_ws, size_t ws_size,
                              hipStream_t stream) {
  const float* ec  = (const float*)d_in[0];
  const float* t12 = (const float*)d_in[1];
  const float* t13 = (const float*)d_in[2];
  const float* t23 = (const float*)d_in[3];
  const int* c12   = (const int*)d_in[4];
  const int* c13   = (const int*)d_in[5];
  const int* c23   = (const int*)d_in[6];
  const float* cnt = (const float*)d_in[7];
  const int* ei    = (const int*)d_in[8];
  const float* W1  = (const float*)d_in[9];
  const float* b1  = (const float*)d_in[10];
  const float* W2  = (const float*)d_in[11];
  const float* b2  = (const float*)d_in[12];
  const float* Wout = (const float*)d_in[13];
  const float* bout = (const float*)d_in[14];

  const int E = in_sizes[0];
  const int T = in_sizes[1];
  const int M = in_sizes[8] / 2;
  const int NB = (T + BS - 1) / BS;

  float* oec = (float*)d_out;
  float* o12 = oec + E;
  float* o13 = o12 + T;
  float* o23 = o13 + T;

  // workspace (~156 MB):
  // tri4[4T] | G4[4T] | srt[M] | rptr[T+1] | msg[E] | EV[4M floats, 64MB]
  // icnt/cursor/bsum/boff alias the EV region (all dead before first k_gather).
  float4* tri4 = (float4*)d_ws;
  float4* G4   = tri4 + T;
  int*    srt  = (int*)(G4 + T);
  int*    rptr = srt + M;
  float*  msg  = (float*)(rptr + (T + 1));
  float4* EV   = (float4*)(msg + E);
  int*    icnt = (int*)EV;        // aliases EV: dead after k_scan3
  int*    curs = icnt + T;        // aliases EV: dead after k_fill
  int*    bsum = curs + T;        // aliases EV: dead after k_scan3
  int*    boff = bsum + NB;

  auto blocks = [](long n) { return (int)((n + BS - 1) / BS); };

  // build CSR (counting sort by dst)
  k_zero_i<<<blocks(T), BS, 0, stream>>>(icnt, T);
  k_count<<<blocks(M), BS, 0, stream>>>(ei, icnt, M);
  k_bsum<<<NB, BS, 0, stream>>>(icnt, bsum, T);
  k_scanb<<<1, BS, 0, stream>>>(bsum, boff, NB);
  k_scan3<<<NB, BS, 0, stream>>>(icnt, boff, rptr, T, M);
  k_copy_i<<<blocks(T), BS, 0, stream>>>(rptr, curs, T);
  k_fill<<<blocks(M), BS, 0, stream>>>(ei, curs, srt, M);

  // step 1 (edge->triplet messages), packed with dis in .w
  k_msg<<<blocks(E), BS, 0, stream>>>(ec, cnt, msg, E);
  k_step1pack<<<blocks(T), BS, 0, stream>>>(msg, t12, t13, t23, c12, c13, c23,
                                            rptr, tri4, T);

  // layer 1: throughput gather, then sequential aggregate
  k_gather<<<blocks((M + 1) / 2), BS, 0, stream>>>(srt, tri4, EV, M);
  k_agg1c<<<blocks(T), BS, 0, stream>>>(rptr, EV, tri4, G4, T);

  // layer 2: throughput gather, then fused sequential layer2 + head + scatter
  k_gather<<<blocks((M + 1) / 2), BS, 0, stream>>>(srt, G4, EV, M);
  k_initec<<<blocks(E), BS, 0, stream>>>(ec, cnt, oec, E);
  k_l2head<<<blocks(T), BS, 0, stream>>>(rptr, EV, G4, tri4,
                                         W1, b1, W2, b2, Wout, bout,
                                         c12, c13, c23, o12, o13, o23, oec, T);
}

// Round 5
// 1084.520 us; speedup vs baseline: 1.0656x; 1.0656x over previous
//
#include <hip/hip_runtime.h>
#include <math.h>

#define HID 32
#define BS 256

// ---------------- structure-building kernels ----------------

__global__ void k_zero_i(int* __restrict__ p, int n) {
  int i = blockIdx.x * BS + threadIdx.x;
  if (i < n) p[i] = 0;
}

// cnt[dst]++ over M edges
__global__ void k_count(const int* __restrict__ ei, int* __restrict__ cnt, int M) {
  int e = blockIdx.x * BS + threadIdx.x;
  if (e < M) atomicAdd(&cnt[ei[M + e]], 1);
}

// per-block sums of cnt -> bsum[NB]
__global__ void k_bsum(const int* __restrict__ cnt, int* __restrict__ bsum, int T) {
  __shared__ int s[BS];
  int i = blockIdx.x * BS + threadIdx.x;
  s[threadIdx.x] = (i < T) ? cnt[i] : 0;
  __syncthreads();
  for (int off = BS / 2; off > 0; off >>= 1) {
    if (threadIdx.x < off) s[threadIdx.x] += s[threadIdx.x + off];
    __syncthreads();
  }
  if (threadIdx.x == 0) bsum[blockIdx.x] = s[0];
}

// single-block exclusive scan of bsum[0..NB) -> boff[0..NB)
__global__ void k_scanb(const int* __restrict__ bsum, int* __restrict__ boff, int NB) {
  __shared__ int buf[BS];
  __shared__ int run;
  if (threadIdx.x == 0) run = 0;
  __syncthreads();
  for (int base = 0; base < NB; base += BS) {
    int i = base + threadIdx.x;
    int v = (i < NB) ? bsum[i] : 0;
    buf[threadIdx.x] = v;
    __syncthreads();
    for (int off = 1; off < BS; off <<= 1) {
      int t = buf[threadIdx.x];
      int u = (threadIdx.x >= off) ? buf[threadIdx.x - off] : 0;
      __syncthreads();
      buf[threadIdx.x] = t + u;
      __syncthreads();
    }
    int incl = buf[threadIdx.x];
    if (i < NB) boff[i] = run + incl - v;  // exclusive
    __syncthreads();
    if (threadIdx.x == BS - 1) run += buf[BS - 1];
    __syncthreads();
  }
}

// row_ptr[i] = boff[blk] + in-block exclusive scan of cnt; also seeds cursor
__global__ void k_scan3(const int* __restrict__ cnt, const int* __restrict__ boff,
                        int* __restrict__ row_ptr, int* __restrict__ cursor,
                        int T, int M) {
  __shared__ int buf[BS];
  int i = blockIdx.x * BS + threadIdx.x;
  int v = (i < T) ? cnt[i] : 0;
  buf[threadIdx.x] = v;
  __syncthreads();
  for (int off = 1; off < BS; off <<= 1) {
    int t = buf[threadIdx.x];
    int u = (threadIdx.x >= off) ? buf[threadIdx.x - off] : 0;
    __syncthreads();
    buf[threadIdx.x] = t + u;
    __syncthreads();
  }
  int incl = buf[threadIdx.x];
  if (i < T) {
    int rp = boff[blockIdx.x] + incl - v;
    row_ptr[i] = rp;
    cursor[i] = rp;
  }
  if (i == 0) row_ptr[T] = M;
}

// scatter src indices into CSR order by dst
__global__ void k_fill(const int* __restrict__ ei, int* __restrict__ cursor,
                       int* __restrict__ srt, int M) {
  int e = blockIdx.x * BS + threadIdx.x;
  if (e >= M) return;
  int s = ei[e], d = ei[M + e];
  int pos = atomicAdd(&cursor[d], 1);
  srt[pos] = s;
}

// ---------------- math kernels ----------------

// msg[e] = ec[e]/cnt[e]; oec[e] = (cnt>0) ? 0 : ec  (one pass over E)
__global__ void k_prep_e(const float* __restrict__ ec, const float* __restrict__ cnt,
                         float* __restrict__ msg, float* __restrict__ oec, int E) {
  int i = blockIdx.x * BS + threadIdx.x;
  if (i >= E) return;
  float c = cnt[i], v = ec[i];
  msg[i] = v / c;
  oec[i] = (c > 0.0f) ? 0.0f : v;
}

// step 1: tri4[i] = (t12 + msg[c12], t13 + msg[c13], t23 + msg[c23], dis_i)
__global__ void k_step1pack(const float* __restrict__ msg,
                            const float* __restrict__ t12, const float* __restrict__ t13,
                            const float* __restrict__ t23,
                            const int* __restrict__ c12, const int* __restrict__ c13,
                            const int* __restrict__ c23,
                            const int* __restrict__ row_ptr,
                            float4* __restrict__ tri4, int T) {
  int i = blockIdx.x * BS + threadIdx.x;
  if (i >= T) return;
  int a = c12[i], b = c13[i], c = c23[i];
  float4 v;
  v.x = t12[i] + msg[a];
  v.y = t13[i] + msg[b];
  v.z = t23[i] + msg[c];
  v.w = rsqrtf((float)(row_ptr[i + 1] - row_ptr[i]) + 1.0f);
  tri4[i] = v;
}

// edge-parallel gather: EV[e] = src[srt[e]]  (independent per-lane gathers ->
// throughput-regime line fills, not latency-regime)
__global__ __launch_bounds__(BS) void k_gather(const int* __restrict__ srt,
                                               const float4* __restrict__ src,
                                               float4* __restrict__ EV, int M) {
  int t = blockIdx.x * BS + threadIdx.x;
  int half = (M + 1) >> 1;
  if (t >= half) return;
  int t2 = t + half;
  int s0 = srt[t];
  int s1 = (t2 < M) ? srt[t2] : s0;
  float4 v0 = src[s0];
  float4 v1 = src[s1];
  EV[t] = v0;
  if (t2 < M) EV[t2] = v1;
}

// layer-1 aggregate, sequential consume of EV
__global__ __launch_bounds__(BS) void k_agg1c(const int* __restrict__ row_ptr,
                                              const float4* __restrict__ EV,
                                              const float4* __restrict__ tri4,
                                              float4* __restrict__ G4, int T) {
  int i = blockIdx.x * BS + threadIdx.x;
  if (i >= T) return;
  int r0 = row_ptr[i], r1 = row_ptr[i + 1];
  float4 ts = tri4[i];
  float di = ts.w;
  float d2 = di * di;
  float ax = ts.x * d2, ay = ts.y * d2, az = ts.z * d2;
  for (int e = r0; e < r1; ++e) {
    float4 v = EV[e];
    float w = v.w * di;
    ax = fmaf(v.x, w, ax);
    ay = fmaf(v.y, w, ay);
    az = fmaf(v.z, w, az);
  }
  float4 o;
  o.x = ax; o.y = ay; o.z = az; o.w = di;
  G4[i] = o;
}

// fused layer2 + head + scatter. NO LDS: weights are read with wave-uniform
// indices straight from global -> scalar loads (SGPR operands to v_fma),
// freeing the LDS pipe entirely (round-4 bottleneck: ~1024 broadcast
// ds_read_b32 per wave ~= the whole 381us).
__global__ __launch_bounds__(BS) void k_l2head(
    const int* __restrict__ row_ptr, const float4* __restrict__ EV,
    const float4* __restrict__ G4, const float4* __restrict__ tri4,
    const float* __restrict__ W1, const float* __restrict__ b1,
    const float* __restrict__ W2, const float* __restrict__ b2,
    const float* __restrict__ Wout, const float* __restrict__ bout,
    const int* __restrict__ c12, const int* __restrict__ c13,
    const int* __restrict__ c23,
    float* __restrict__ o12, float* __restrict__ o13, float* __restrict__ o23,
    float* __restrict__ oec, int T) {
  int i = blockIdx.x * BS + threadIdx.x;
  if (i >= T) return;
  int r0 = row_ptr[i], r1 = row_ptr[i + 1];
  float4 gi = G4[i];
  float di = gi.w;
  float d2 = di * di;

  // layer-2 aggregate in registers; h1 recomputed on the fly from G4
  float acc[HID];
#pragma unroll
  for (int h = 0; h < HID; ++h) {
    float v = fmaf(gi.x, W1[h], fmaf(gi.y, W1[HID + h], fmaf(gi.z, W1[2 * HID + h], b1[h])));
    acc[h] = fmaxf(v, 0.0f) * d2;  // self-loop term
  }
  for (int e = r0; e < r1; ++e) {
    float4 g = EV[e];
    float w = g.w * di;
#pragma unroll
    for (int h = 0; h < HID; ++h) {
      float v = fmaf(g.x, W1[h], fmaf(g.y, W1[HID + h], fmaf(g.z, W1[2 * HID + h], b1[h])));
      acc[h] = fmaf(fmaxf(v, 0.0f), w, acc[h]);
    }
  }

  // z = acc @ W2 + b2 : h-outer so W2 is consumed sequentially (s_load-friendly)
  // and 32 independent z-chains give the VALU full ILP.
  float z[HID];
#pragma unroll
  for (int hp = 0; hp < HID; ++hp) z[hp] = b2[hp];
#pragma unroll
  for (int h = 0; h < HID; ++h) {
    float a = acc[h];
#pragma unroll
    for (int hp = 0; hp < HID; ++hp) z[hp] = fmaf(a, W2[h * HID + hp], z[hp]);
  }

  float d0 = bout[0], d1 = bout[1], dd2 = bout[2];
#pragma unroll
  for (int hp = 0; hp < HID; ++hp) {
    float v = fmaxf(z[hp], 0.0f);
    d0 = fmaf(v, Wout[hp * 3 + 0], d0);
    d1 = fmaf(v, Wout[hp * 3 + 1], d1);
    dd2 = fmaf(v, Wout[hp * 3 + 2], dd2);
  }

  float4 tp = tri4[i];
  o12[i] = tp.x - d0;
  o13[i] = tp.y - d1;
  o23[i] = tp.z - dd2;
  unsafeAtomicAdd(&oec[c12[i]], d0);
  unsafeAtomicAdd(&oec[c13[i]], d1);
  unsafeAtomicAdd(&oec[c23[i]], dd2);
}

// ---------------- launch ----------------

extern "C" void kernel_launch(void* const* d_in, const int* in_sizes, int n_in,
                              void* d_out, int out_size, void* d_ws, size_t ws_size,
                              hipStream_t stream) {
  const float* ec  = (const float*)d_in[0];
  const float* t12 = (const float*)d_in[1];
  const float* t13 = (const float*)d_in[2];
  const float* t23 = (const float*)d_in[3];
  const int* c12   = (const int*)d_in[4];
  const int* c13   = (const int*)d_in[5];
  const int* c23   = (const int*)d_in[6];
  const float* cnt = (const float*)d_in[7];
  const int* ei    = (const int*)d_in[8];
  const float* W1  = (const float*)d_in[9];
  const float* b1  = (const float*)d_in[10];
  const float* W2  = (const float*)d_in[11];
  const float* b2  = (const float*)d_in[12];
  const float* Wout = (const float*)d_in[13];
  const float* bout = (const float*)d_in[14];

  const int E = in_sizes[0];
  const int T = in_sizes[1];
  const int M = in_sizes[8] / 2;
  const int NB = (T + BS - 1) / BS;

  float* oec = (float*)d_out;
  float* o12 = oec + E;
  float* o13 = o12 + T;
  float* o23 = o13 + T;

  // workspace (~156 MB):
  // tri4[4T] | G4[4T] | srt[M] | rptr[T+1] | msg[E] | EV[4M floats, 64MB]
  // icnt/cursor/bsum/boff alias the EV region (all dead before first k_gather).
  float4* tri4 = (float4*)d_ws;
  float4* G4   = tri4 + T;
  int*    srt  = (int*)(G4 + T);
  int*    rptr = srt + M;
  float*  msg  = (float*)(rptr + (T + 1));
  float4* EV   = (float4*)(msg + E);
  int*    icnt = (int*)EV;        // aliases EV: dead after k_scan3
  int*    curs = icnt + T;        // aliases EV: dead after k_fill
  int*    bsum = curs + T;        // aliases EV: dead after k_scan3
  int*    boff = bsum + NB;

  auto blocks = [](long n) { return (int)((n + BS - 1) / BS); };

  // build CSR (counting sort by dst)
  k_zero_i<<<blocks(T), BS, 0, stream>>>(icnt, T);
  k_count<<<blocks(M), BS, 0, stream>>>(ei, icnt, M);
  k_bsum<<<NB, BS, 0, stream>>>(icnt, bsum, T);
  k_scanb<<<1, BS, 0, stream>>>(bsum, boff, NB);
  k_scan3<<<NB, BS, 0, stream>>>(icnt, boff, rptr, curs, T, M);
  k_fill<<<blocks(M), BS, 0, stream>>>(ei, curs, srt, M);

  // per-edge prep (msg + output edge-cost init), then step-1 pack
  k_prep_e<<<blocks(E), BS, 0, stream>>>(ec, cnt, msg, oec, E);
  k_step1pack<<<blocks(T), BS, 0, stream>>>(msg, t12, t13, t23, c12, c13, c23,
                                            rptr, tri4, T);

  // layer 1: throughput gather, then sequential aggregate
  k_gather<<<blocks((M + 1) / 2), BS, 0, stream>>>(srt, tri4, EV, M);
  k_agg1c<<<blocks(T), BS, 0, stream>>>(rptr, EV, tri4, G4, T);

  // layer 2: throughput gather, then fused layer2 + head + scatter
  k_gather<<<blocks((M + 1) / 2), BS, 0, stream>>>(srt, G4, EV, M);
  k_l2head<<<blocks(T), BS, 0, stream>>>(rptr, EV, G4, tri4,
                                         W1, b1, W2, b2, Wout, bout,
                                         c12, c13, c23, o12, o13, o23, oec, T);
}

// Round 6
// 843.072 us; speedup vs baseline: 1.3708x; 1.2864x over previous
//
#include <hip/hip_runtime.h>
#include <math.h>

#define HID 32
#define BS 256

// ---- bucketed counting-sort parameters ----
#define NPB 4096          // nodes per bucket (dst range per bucket)
#define NBK_MAX 1024      // LDS sizing cap for bucket count
#define EBT 8192          // edges per scatter tile
#define CAP 11776         // per-bucket LDS srt capacity (mean 8192, +40 sigma)

// ---------------- utility ----------------

__global__ void k_zero_i(int* __restrict__ p, int n) {
  int i = blockIdx.x * BS + threadIdx.x;
  if (i < n) p[i] = 0;
}

// ---------------- bucketed sort: pass A — global bucket histogram ----------------

__global__ __launch_bounds__(BS) void k_bhist(const int* __restrict__ ei,
                                              int* __restrict__ gh, int M, int NBK) {
  __shared__ int hist[NBK_MAX];
  for (int b = threadIdx.x; b < NBK; b += BS) hist[b] = 0;
  __syncthreads();
  int e0 = blockIdx.x * EBT;
  int n = min(EBT, M - e0);
  for (int k = threadIdx.x; k < n; k += BS) {
    int d = ei[M + e0 + k];
    atomicAdd(&hist[d / NPB], 1);
  }
  __syncthreads();
  for (int b = threadIdx.x; b < NBK; b += BS)
    if (hist[b]) atomicAdd(&gh[b], hist[b]);
}

// ---------------- pass B — single-block scan of bucket sizes ----------------

__global__ __launch_bounds__(BS) void k_bscan(const int* __restrict__ gh,
                                              int* __restrict__ gboff,
                                              int* __restrict__ gcur, int NBK) {
  __shared__ int part[BS];
  int C = (NBK + BS - 1) / BS;
  int s = 0;
  for (int k = 0; k < C; ++k) {
    int idx = threadIdx.x * C + k;
    if (idx < NBK) s += gh[idx];
  }
  part[threadIdx.x] = s;
  __syncthreads();
  for (int off = 1; off < BS; off <<= 1) {
    int v = part[threadIdx.x];
    int u = (threadIdx.x >= off) ? part[threadIdx.x - off] : 0;
    __syncthreads();
    part[threadIdx.x] = v + u;
    __syncthreads();
  }
  int run = (threadIdx.x > 0) ? part[threadIdx.x - 1] : 0;
  for (int k = 0; k < C; ++k) {
    int idx = threadIdx.x * C + k;
    if (idx < NBK) {
      gboff[idx] = run;
      gcur[idx] = run;
      run += gh[idx];
    }
  }
  if (threadIdx.x == BS - 1) gboff[NBK] = run;  // == M
}

// ---------------- pass C — tiled scatter of (src,dst) pairs into bucket runs ----------------
// Each tile reserves a contiguous run per bucket (one global atomic/bucket/tile),
// so writes land in ~128B contiguous runs -> full-line dirtying, no 16x amplification.

__global__ __launch_bounds__(BS) void k_bscatter(const int* __restrict__ ei,
                                                 int* __restrict__ gcur,
                                                 int2* __restrict__ P, int M, int NBK) {
  __shared__ int hist[NBK_MAX];
  __shared__ int excl[NBK_MAX];
  __shared__ int curs[NBK_MAX];
  __shared__ int base[NBK_MAX];
  __shared__ int part[BS];
  for (int b = threadIdx.x; b < NBK; b += BS) hist[b] = 0;
  __syncthreads();
  int e0 = blockIdx.x * EBT;
  int n = min(EBT, M - e0);
  // phase A: local histogram
  for (int k = threadIdx.x; k < n; k += BS) {
    int d = ei[M + e0 + k];
    atomicAdd(&hist[d / NPB], 1);
  }
  __syncthreads();
  // phase B: local exclusive scan (chunked)
  int C = (NBK + BS - 1) / BS;
  int s = 0;
  for (int k = 0; k < C; ++k) {
    int idx = threadIdx.x * C + k;
    if (idx < NBK) s += hist[idx];
  }
  part[threadIdx.x] = s;
  __syncthreads();
  for (int off = 1; off < BS; off <<= 1) {
    int v = part[threadIdx.x];
    int u = (threadIdx.x >= off) ? part[threadIdx.x - off] : 0;
    __syncthreads();
    part[threadIdx.x] = v + u;
    __syncthreads();
  }
  int run = (threadIdx.x > 0) ? part[threadIdx.x - 1] : 0;
  for (int k = 0; k < C; ++k) {
    int idx = threadIdx.x * C + k;
    if (idx < NBK) {
      excl[idx] = run;
      curs[idx] = run;
      run += hist[idx];
    }
  }
  __syncthreads();
  // phase C: reserve global runs
  for (int b = threadIdx.x; b < NBK; b += BS)
    base[b] = hist[b] ? atomicAdd(&gcur[b], hist[b]) : 0;
  __syncthreads();
  // phase D: place pairs
  for (int k = threadIdx.x; k < n; k += BS) {
    int sidx = ei[e0 + k];
    int d = ei[M + e0 + k];
    int b = d / NPB;
    int pos = atomicAdd(&curs[b], 1);
    int gpos = base[b] + (pos - excl[b]);
    P[gpos] = make_int2(sidx, d);
  }
}

// ---------------- pass D — per-bucket LDS counting sort -> row_ptr + srt ----------------

__global__ __launch_bounds__(BS) void k_bfinal(const int2* __restrict__ P,
                                               const int* __restrict__ gboff,
                                               int* __restrict__ row_ptr,
                                               int* __restrict__ srt, int T, int M,
                                               int NBK) {
  __shared__ int cnt[NPB];    // counts -> exclusive cursor (in place)
  __shared__ int lsrt[CAP];
  __shared__ int part[BS];
  int b = blockIdx.x;
  int d0 = b * NPB;
  int nodesHere = min(NPB, T - d0);
  int p0 = gboff[b], p1 = gboff[b + 1];
  int nE = p1 - p0;
  for (int j = threadIdx.x; j < NPB; j += BS) cnt[j] = 0;
  __syncthreads();
  // count per node
  for (int j = threadIdx.x; j < nE; j += BS) {
    int2 p = P[p0 + j];
    atomicAdd(&cnt[p.y - d0], 1);
  }
  __syncthreads();
  // exclusive scan over NPB (chunk of 16 per thread), write row_ptr, cnt -> cursor
  const int CN = NPB / BS;  // 16
  int s = 0;
#pragma unroll
  for (int k = 0; k < CN; ++k) s += cnt[threadIdx.x * CN + k];
  part[threadIdx.x] = s;
  __syncthreads();
  for (int off = 1; off < BS; off <<= 1) {
    int v = part[threadIdx.x];
    int u = (threadIdx.x >= off) ? part[threadIdx.x - off] : 0;
    __syncthreads();
    part[threadIdx.x] = v + u;
    __syncthreads();
  }
  int run = (threadIdx.x > 0) ? part[threadIdx.x - 1] : 0;
#pragma unroll
  for (int k = 0; k < CN; ++k) {
    int idx = threadIdx.x * CN + k;
    int c = cnt[idx];
    cnt[idx] = run;  // exclusive position (cursor)
    if (idx < nodesHere) row_ptr[d0 + idx] = p0 + run;
    run += c;
  }
  if (b == NBK - 1 && threadIdx.x == 0) row_ptr[T] = M;
  __syncthreads();
  if (nE <= CAP) {
    for (int j = threadIdx.x; j < nE; j += BS) {
      int2 p = P[p0 + j];
      int pos = atomicAdd(&cnt[p.y - d0], 1);
      lsrt[pos] = p.x;
    }
    __syncthreads();
    for (int j = threadIdx.x; j < nE; j += BS) srt[p0 + j] = lsrt[j];
  } else {  // overflow fallback (statistically unreachable)
    for (int j = threadIdx.x; j < nE; j += BS) {
      int2 p = P[p0 + j];
      int pos = atomicAdd(&cnt[p.y - d0], 1);
      srt[p0 + pos] = p.x;
    }
  }
}

// ---------------- math kernels ----------------

// msg[e] = ec[e]/cnt[e]; oec[e] = (cnt>0) ? 0 : ec  (one pass over E)
__global__ void k_prep_e(const float* __restrict__ ec, const float* __restrict__ cnt,
                         float* __restrict__ msg, float* __restrict__ oec, int E) {
  int i = blockIdx.x * BS + threadIdx.x;
  if (i >= E) return;
  float c = cnt[i], v = ec[i];
  msg[i] = v / c;
  oec[i] = (c > 0.0f) ? 0.0f : v;
}

// step 1: tri4[i] = (t12 + msg[c12], t13 + msg[c13], t23 + msg[c23], dis_i)
__global__ void k_step1pack(const float* __restrict__ msg,
                            const float* __restrict__ t12, const float* __restrict__ t13,
                            const float* __restrict__ t23,
                            const int* __restrict__ c12, const int* __restrict__ c13,
                            const int* __restrict__ c23,
                            const int* __restrict__ row_ptr,
                            float4* __restrict__ tri4, int T) {
  int i = blockIdx.x * BS + threadIdx.x;
  if (i >= T) return;
  int a = c12[i], b = c13[i], c = c23[i];
  float4 v;
  v.x = t12[i] + msg[a];
  v.y = t13[i] + msg[b];
  v.z = t23[i] + msg[c];
  v.w = rsqrtf((float)(row_ptr[i + 1] - row_ptr[i]) + 1.0f);
  tri4[i] = v;
}

// edge-parallel gather: EV[e] = src[srt[e]]  (throughput-regime line fills)
__global__ __launch_bounds__(BS) void k_gather(const int* __restrict__ srt,
                                               const float4* __restrict__ src,
                                               float4* __restrict__ EV, int M) {
  int t = blockIdx.x * BS + threadIdx.x;
  int half = (M + 1) >> 1;
  if (t >= half) return;
  int t2 = t + half;
  int s0 = srt[t];
  int s1 = (t2 < M) ? srt[t2] : s0;
  float4 v0 = src[s0];
  float4 v1 = src[s1];
  EV[t] = v0;
  if (t2 < M) EV[t2] = v1;
}

// layer-1 aggregate, sequential consume of EV
__global__ __launch_bounds__(BS) void k_agg1c(const int* __restrict__ row_ptr,
                                              const float4* __restrict__ EV,
                                              const float4* __restrict__ tri4,
                                              float4* __restrict__ G4, int T) {
  int i = blockIdx.x * BS + threadIdx.x;
  if (i >= T) return;
  int r0 = row_ptr[i], r1 = row_ptr[i + 1];
  float4 ts = tri4[i];
  float di = ts.w;
  float d2 = di * di;
  float ax = ts.x * d2, ay = ts.y * d2, az = ts.z * d2;
  for (int e = r0; e < r1; ++e) {
    float4 v = EV[e];
    float w = v.w * di;
    ax = fmaf(v.x, w, ax);
    ay = fmaf(v.y, w, ay);
    az = fmaf(v.z, w, az);
  }
  float4 o;
  o.x = ax; o.y = ay; o.z = az; o.w = di;
  G4[i] = o;
}

// fused layer2 + head + scatter. Weights via wave-uniform global reads (scalar
// loads). z computed in 4 chunks of 8 to keep live VGPRs ~48;
// __launch_bounds__(256,4) caps occupancy at 16 waves/CU -> VGPR budget 128
// (round-5's 40-VGPR allocation forced spill shuffles: VALU ~2x inflated).
__global__ __launch_bounds__(BS, 4) void k_l2head(
    const int* __restrict__ row_ptr, const float4* __restrict__ EV,
    const float4* __restrict__ G4, const float4* __restrict__ tri4,
    const float* __restrict__ W1, const float* __restrict__ b1,
    const float* __restrict__ W2, const float* __restrict__ b2,
    const float* __restrict__ Wout, const float* __restrict__ bout,
    const int* __restrict__ c12, const int* __restrict__ c13,
    const int* __restrict__ c23,
    float* __restrict__ o12, float* __restrict__ o13, float* __restrict__ o23,
    float* __restrict__ oec, int T) {
  int i = blockIdx.x * BS + threadIdx.x;
  if (i >= T) return;
  int r0 = row_ptr[i], r1 = row_ptr[i + 1];
  float4 gi = G4[i];
  float di = gi.w;
  float d2 = di * di;

  // layer-2 aggregate in registers; h1 recomputed on the fly from G4
  float acc[HID];
#pragma unroll
  for (int h = 0; h < HID; ++h) {
    float v = fmaf(gi.x, W1[h], fmaf(gi.y, W1[HID + h], fmaf(gi.z, W1[2 * HID + h], b1[h])));
    acc[h] = fmaxf(v, 0.0f) * d2;  // self-loop term
  }
  for (int e = r0; e < r1; ++e) {
    float4 g = EV[e];
    float w = g.w * di;
#pragma unroll
    for (int h = 0; h < HID; ++h) {
      float v = fmaf(g.x, W1[h], fmaf(g.y, W1[HID + h], fmaf(g.z, W1[2 * HID + h], b1[h])));
      acc[h] = fmaf(fmaxf(v, 0.0f), w, acc[h]);
    }
  }

  // z = acc @ W2 + b2 in 4 chunks of 8; head folded per chunk.
  float d0 = bout[0], d1 = bout[1], dd2 = bout[2];
#pragma unroll
  for (int cz = 0; cz < HID / 8; ++cz) {
    float z[8];
#pragma unroll
    for (int j = 0; j < 8; ++j) z[j] = b2[cz * 8 + j];
#pragma unroll
    for (int h = 0; h < HID; ++h) {
      float a = acc[h];
#pragma unroll
      for (int j = 0; j < 8; ++j) z[j] = fmaf(a, W2[h * HID + cz * 8 + j], z[j]);
    }
#pragma unroll
    for (int j = 0; j < 8; ++j) {
      float v = fmaxf(z[j], 0.0f);
      int hp = cz * 8 + j;
      d0 = fmaf(v, Wout[hp * 3 + 0], d0);
      d1 = fmaf(v, Wout[hp * 3 + 1], d1);
      dd2 = fmaf(v, Wout[hp * 3 + 2], dd2);
    }
  }

  float4 tp = tri4[i];
  o12[i] = tp.x - d0;
  o13[i] = tp.y - d1;
  o23[i] = tp.z - dd2;
  unsafeAtomicAdd(&oec[c12[i]], d0);
  unsafeAtomicAdd(&oec[c13[i]], d1);
  unsafeAtomicAdd(&oec[c23[i]], dd2);
}

// ---------------- launch ----------------

extern "C" void kernel_launch(void* const* d_in, const int* in_sizes, int n_in,
                              void* d_out, int out_size, void* d_ws, size_t ws_size,
                              hipStream_t stream) {
  const float* ec  = (const float*)d_in[0];
  const float* t12 = (const float*)d_in[1];
  const float* t13 = (const float*)d_in[2];
  const float* t23 = (const float*)d_in[3];
  const int* c12   = (const int*)d_in[4];
  const int* c13   = (const int*)d_in[5];
  const int* c23   = (const int*)d_in[6];
  const float* cnt = (const float*)d_in[7];
  const int* ei    = (const int*)d_in[8];
  const float* W1  = (const float*)d_in[9];
  const float* b1  = (const float*)d_in[10];
  const float* W2  = (const float*)d_in[11];
  const float* b2  = (const float*)d_in[12];
  const float* Wout = (const float*)d_in[13];
  const float* bout = (const float*)d_in[14];

  const int E = in_sizes[0];
  const int T = in_sizes[1];
  const int M = in_sizes[8] / 2;
  const int NBK = (T + NPB - 1) / NPB;  // 512 for T=2M

  float* oec = (float*)d_out;
  float* o12 = oec + E;
  float* o13 = o12 + T;
  float* o23 = o13 + T;

  // workspace (~156 MB):
  // tri4[4T] | G4[4T] | EV[4M] | srt[M] | rptr[T+1] | msg[E] | gh[NBK] | gboff[NBK+1] | gcur[NBK]
  // P (pairs, 8B x M = 32MB) aliases EV (dead before first k_gather).
  float4* tri4 = (float4*)d_ws;
  float4* G4   = tri4 + T;
  float4* EV   = G4 + T;
  int*    srt  = (int*)(EV + M);
  int*    rptr = srt + M;
  float*  msg  = (float*)(rptr + (T + 1));
  int*    gh   = (int*)(msg + E);
  int*    gboff = gh + NBK;
  int*    gcur  = gboff + (NBK + 1);
  int2*   P    = (int2*)EV;  // aliases EV: dead after k_bfinal

  auto blocks = [](long n) { return (int)((n + BS - 1) / BS); };
  const int tiles = (M + EBT - 1) / EBT;

  // bucketed counting sort by dst -> row_ptr + srt
  k_zero_i<<<blocks(NBK), BS, 0, stream>>>(gh, NBK);
  k_bhist<<<tiles, BS, 0, stream>>>(ei, gh, M, NBK);
  k_bscan<<<1, BS, 0, stream>>>(gh, gboff, gcur, NBK);
  k_bscatter<<<tiles, BS, 0, stream>>>(ei, gcur, P, M, NBK);
  k_bfinal<<<NBK, BS, 0, stream>>>(P, gboff, rptr, srt, T, M, NBK);

  // per-edge prep (msg + output edge-cost init), then step-1 pack
  k_prep_e<<<blocks(E), BS, 0, stream>>>(ec, cnt, msg, oec, E);
  k_step1pack<<<blocks(T), BS, 0, stream>>>(msg, t12, t13, t23, c12, c13, c23,
                                            rptr, tri4, T);

  // layer 1: throughput gather, then sequential aggregate
  k_gather<<<blocks((M + 1) / 2), BS, 0, stream>>>(srt, tri4, EV, M);
  k_agg1c<<<blocks(T), BS, 0, stream>>>(rptr, EV, tri4, G4, T);

  // layer 2: throughput gather, then fused layer2 + head + scatter
  k_gather<<<blocks((M + 1) / 2), BS, 0, stream>>>(srt, G4, EV, M);
  k_l2head<<<blocks(T), BS, 0, stream>>>(rptr, EV, G4, tri4,
                                         W1, b1, W2, b2, Wout, bout,
                                         c12, c13, c23, o12, o13, o23, oec, T);
}